// Round 13
// baseline (66.550 us; speedup 1.0000x reference)
//
#include <hip/hip_runtime.h>
#include <hip/hip_bf16.h>
#include <cstdint>
#include <cstddef>

#define NB 4096     // batch rows
#define NC 1000     // real classes
#define NCP 1024    // padded classes
#define ND 3072     // feature dim
#define NSL 4       // split-K slices
#define KSL (ND / NSL)   // 768
#define BM 256
#define BN 256
#define BKT 64           // K-tile
#define NKT (KSL / BKT)  // 12 K-tiles per slice
#define TILE (256 * 64)  // elems per LDS tile buffer (32 KiB)

typedef __attribute__((ext_vector_type(8))) __bf16 bf16x8;
typedef __attribute__((ext_vector_type(4))) float f32x4;
typedef __attribute__((ext_vector_type(4))) unsigned short u16x4;
typedef __attribute__((ext_vector_type(4))) _Float16 f16x4;
typedef unsigned short u16;

__device__ __forceinline__ u16 f2bf_rne(float x) {
    uint32_t u = __float_as_uint(x);
    uint32_t r = (u + 0x7fffu + ((u >> 16) & 1u)) >> 16;
    return (u16)r;
}

// ---------------------------------------------------------------------------
// Fused convert: blocks [0,NB) convert z rows (z2 = ||z||^2); blocks
// [NB, NB+NCP) convert means rows (rows >= NC zero-padded, m2 = 1e30).
// ---------------------------------------------------------------------------
__global__ __launch_bounds__(256) void convert_all_kernel(
        const float* __restrict__ z, const float* __restrict__ means,
        u16* __restrict__ zb, u16* __restrict__ mb,
        float* __restrict__ z2, float* __restrict__ m2) {
    const int bidx = blockIdx.x;
    const int tid = threadIdx.x;
    const float* src;
    u16* dst;
    float* sq;
    bool pad = false;
    if (bidx < NB) {
        src = z + (size_t)bidx * ND;
        dst = zb + (size_t)bidx * ND;
        sq = z2 + bidx;
    } else {
        const int mr = bidx - NB;
        dst = mb + (size_t)mr * ND;
        sq = m2 + mr;
        src = means + (size_t)mr * ND;
        pad = (mr >= NC);
    }
    if (!pad) {
        const float4* s = (const float4*)src;
        float acc = 0.f;
#pragma unroll
        for (int i = 0; i < 3; ++i) {                // 768 float4 / 256 threads
            const int idx = tid + i * 256;
            float4 v = s[idx];
            acc = fmaf(v.x, v.x, acc);
            acc = fmaf(v.y, v.y, acc);
            acc = fmaf(v.z, v.z, acc);
            acc = fmaf(v.w, v.w, acc);
            u16x4 o;
            o.x = f2bf_rne(v.x); o.y = f2bf_rne(v.y);
            o.z = f2bf_rne(v.z); o.w = f2bf_rne(v.w);
            *(u16x4*)(dst + idx * 4) = o;
        }
#pragma unroll
        for (int off = 32; off > 0; off >>= 1) acc += __shfl_xor(acc, off, 64);
        __shared__ float ssum[4];
        const int wid = tid >> 6, lane = tid & 63;
        if (lane == 0) ssum[wid] = acc;
        __syncthreads();
        if (tid == 0) sq[0] = ssum[0] + ssum[1] + ssum[2] + ssum[3];
    } else {
        u16x4 z4 = (u16x4){0, 0, 0, 0};
#pragma unroll
        for (int i = 0; i < 3; ++i) *(u16x4*)(dst + (tid + i * 256) * 4) = z4;
        if (tid == 0) sq[0] = 1e30f;
    }
}

// ---------------------------------------------------------------------------
// 8-phase 256x256 GEMM (m201 template ported): crossh[s][b][c] = (f16)
// sum over K-slice s of z_b . mu_c.
// 8 waves (512 thr, 2M x 4N), wave tile 128x64, BK-tile 64, 2 dbuf x (A,B)
// x 32 KiB = 128 KiB LDS. Per phase: 12 ds_read_b128 (one quadrant x K=64)
// || 2 global_load_lds (one half-region of a future tile, targeting regions
// whose last reader finished >=1 barrier ago) -> bar -> lgkmcnt(0) ->
// setprio(1) -> 16 MFMA -> setprio(0) -> counted vmcnt -> bar.
// vmcnt(8/6) steady (never 0); peeled last iter drains 6/4/0.
// Swizzle: stage source k-slot s = (lane&7)^(lane>>3); read slot
// pk = (ks*4+kgrp)^(lrow&7)  (R2-verified 0-conflict involution pair).
// ---------------------------------------------------------------------------
#define GLOAD_LDS16(gp, lp)                                            \
    __builtin_amdgcn_global_load_lds(                                  \
        (const __attribute__((address_space(1))) void*)(gp),           \
        (__attribute__((address_space(3))) void*)(lp), 16, 0, 0)

__global__ __launch_bounds__(512, 1) void gemm_kernel(
        const u16* __restrict__ zb, const u16* __restrict__ mb,
        _Float16* __restrict__ crossh) {
    __shared__ u16 As[2 * TILE];   // 64 KiB
    __shared__ u16 Bs[2 * TILE];   // 64 KiB

    const int tid  = threadIdx.x;
    const int wid  = tid >> 6;
    const int lane = tid & 63;
    const int wm   = wid >> 2;           // wave row 0..1 (128 rows each)
    const int wn   = wid & 3;            // wave col 0..3 (64 cols each)
    const int lrow = lane & 15;
    const int kgrp = lane >> 4;

    // XCD-chunked work: 32 consecutive w per XCD.
    const int bid = blockIdx.x;
    const int w = (bid & 7) * 32 + (bid >> 3);
    const int ksl  = w >> 6;
    const int rem  = w & 63;
    const int brow = (rem >> 2) * BM;    // 16 brow panels
    const int bcol = (rem & 3) * BN;     // 4 bcol panels
    const int kbase = ksl * KSL;

    f32x4 acc[8][4];
#pragma unroll
    for (int m = 0; m < 8; ++m)
#pragma unroll
        for (int n = 0; n < 4; ++n) acc[m][n] = (f32x4){0.f, 0.f, 0.f, 0.f};

    // -------- staging maps (per-lane global src, linear LDS dest) --------
    const int l3  = lane >> 3;                   // 0..7
    const int sl8 = ((lane & 7) ^ l3) * 8;       // swizzled global k-slot (elems)

    // A-half(qm): rows {qm*64+[0,64)} u {128+qm*64+[0,64)}; inst j covers 64 rows.
    const u16* gAh[2][2];
    int AbL[2][2];
#pragma unroll
    for (int qm = 0; qm < 2; ++qm)
#pragma unroll
        for (int j = 0; j < 2; ++j) {
            const int r = qm * 64 + j * 128 + wid * 8 + l3;
            gAh[qm][j] = zb + (size_t)(brow + r) * ND + kbase + sl8;
            AbL[qm][j] = (qm * 64 + j * 128 + wid * 8) * 64;
        }
    // B-half(qn): rows {qn*32 + 64*g + [0,32)} for g=0..3; 2 insts.
    const u16* gBh[2][2];
    int BbL[2][2];
#pragma unroll
    for (int qn = 0; qn < 2; ++qn)
#pragma unroll
        for (int j = 0; j < 2; ++j) {
            const int rw0 = j * 64 + wid * 8;            // lane-0 region row
            const int r0  = (rw0 & 31) + (rw0 >> 5) * 64 + qn * 32;
            gBh[qn][j] = mb + (size_t)(bcol + r0 + l3) * ND + kbase + sl8;
            BbL[qn][j] = r0 * 64;
        }

#define STAGE_A(qm, buf, tt) do {                                        \
        GLOAD_LDS16(gAh[qm][0] + (tt) * 64, As + (buf) * TILE + AbL[qm][0]); \
        GLOAD_LDS16(gAh[qm][1] + (tt) * 64, As + (buf) * TILE + AbL[qm][1]); \
    } while (0)
#define STAGE_B(qn, buf, tt) do {                                        \
        GLOAD_LDS16(gBh[qn][0] + (tt) * 64, Bs + (buf) * TILE + BbL[qn][0]); \
        GLOAD_LDS16(gBh[qn][1] + (tt) * 64, Bs + (buf) * TILE + BbL[qn][1]); \
    } while (0)

#define VM8 asm volatile("s_waitcnt vmcnt(8)" ::: "memory")
#define VM6 asm volatile("s_waitcnt vmcnt(6)" ::: "memory")
#define VM4 asm volatile("s_waitcnt vmcnt(4)" ::: "memory")
#define VM0 asm volatile("s_waitcnt vmcnt(0)" ::: "memory")

#define PHASE(buf, qm, qn, STG, VMW) do {                                \
        const u16* Ac = As + (buf) * TILE;                               \
        const u16* Bc = Bs + (buf) * TILE;                               \
        bf16x8 a[2][4];                                                  \
        bf16x8 bbf[2][2];                                                \
        _Pragma("unroll")                                                \
        for (int ks = 0; ks < 2; ++ks) {                                 \
            const int pk8 = ((ks * 4 + kgrp) ^ (lrow & 7)) * 8;          \
            _Pragma("unroll")                                            \
            for (int m = 0; m < 4; ++m)                                  \
                a[ks][m] = *(const bf16x8*)&Ac[(wm * 128 + (qm) * 64 + m * 16 + lrow) * 64 + pk8]; \
            _Pragma("unroll")                                            \
            for (int n = 0; n < 2; ++n)                                  \
                bbf[ks][n] = *(const bf16x8*)&Bc[(wn * 64 + (qn) * 32 + n * 16 + lrow) * 64 + pk8]; \
        }                                                                \
        STG;                                                             \
        __builtin_amdgcn_s_barrier();                                    \
        asm volatile("s_waitcnt lgkmcnt(0)" ::: "memory");               \
        __builtin_amdgcn_sched_barrier(0);                               \
        __builtin_amdgcn_s_setprio(1);                                   \
        _Pragma("unroll")                                                \
        for (int ks = 0; ks < 2; ++ks)                                   \
            _Pragma("unroll")                                            \
            for (int m = 0; m < 4; ++m)                                  \
                _Pragma("unroll")                                        \
                for (int n = 0; n < 2; ++n)                              \
                    acc[(qm) * 4 + m][(qn) * 2 + n] =                    \
                        __builtin_amdgcn_mfma_f32_16x16x32_bf16(         \
                            a[ks][m], bbf[ks][n],                        \
                            acc[(qm) * 4 + m][(qn) * 2 + n], 0, 0, 0);   \
        __builtin_amdgcn_s_setprio(0);                                   \
        VMW;                                                             \
        __builtin_amdgcn_s_barrier();                                    \
    } while (0)

    // prologue: tile0 fully into buf0, tile1's A0,B0 into buf1 (12 loads)
    STAGE_A(0, 0, 0); STAGE_B(0, 0, 0);
    STAGE_A(1, 0, 0); STAGE_B(1, 0, 0);
    STAGE_A(0, 1, 1); STAGE_B(0, 1, 1);
    VM8;                                 // tile0 A0,B0 landed
    __builtin_amdgcn_s_barrier();

    // steady iters: tiles ta=2i (buf0), tb=2i+1 (buf1)
    for (int i = 0; i < 5; ++i) {
        const int ta = 2 * i, tb = 2 * i + 1;
        PHASE(0, 0, 0, STAGE_A(1, 1, tb),     VM6);   // ph1
        PHASE(0, 0, 1, STAGE_B(1, 1, tb),         );  // ph2
        PHASE(0, 1, 0, STAGE_A(0, 0, ta + 2),     );  // ph3
        PHASE(0, 1, 1, STAGE_B(0, 0, ta + 2), VM8);   // ph4
        PHASE(1, 0, 0, STAGE_A(1, 0, ta + 2), VM6);   // ph5
        PHASE(1, 0, 1, STAGE_B(1, 0, ta + 2),     );  // ph6
        PHASE(1, 1, 0, STAGE_A(0, 1, tb + 2),     );  // ph7
        PHASE(1, 1, 1, STAGE_B(0, 1, tb + 2), VM8);   // ph8
    }
    // peeled last iter: ta=10, tb=11 (only tb's A1,B1 remain to stage)
    PHASE(0, 0, 0, STAGE_A(1, 1, 11), VM6);
    PHASE(0, 0, 1, STAGE_B(1, 1, 11),     );
    PHASE(0, 1, 0, ;,                     );
    PHASE(0, 1, 1, ;,                 VM4);
    PHASE(1, 0, 0, ;,                 VM0);
    PHASE(1, 0, 1, ;,                     );
    PHASE(1, 1, 0, ;,                     );
    PHASE(1, 1, 1, ;,                     );

#undef PHASE
#undef STAGE_A
#undef STAGE_B

    // epilogue: C/D layout col = lane&15, row = (lane>>4)*4 + r  (f16 partial)
    _Float16* outp = crossh + (size_t)ksl * NB * NCP;
#pragma unroll
    for (int qm = 0; qm < 2; ++qm)
#pragma unroll
        for (int m = 0; m < 4; ++m)
#pragma unroll
            for (int qn = 0; qn < 2; ++qn)
#pragma unroll
                for (int n = 0; n < 2; ++n) {
                    const int gcol = bcol + wn * 64 + qn * 32 + n * 16 + lrow;
#pragma unroll
                    for (int r = 0; r < 4; ++r) {
                        const int grow = brow + wm * 128 + qm * 64 + m * 16 + kgrp * 4 + r;
                        outp[(size_t)grow * NCP + gcol] =
                            (_Float16)acc[qm * 4 + m][qn * 2 + n][r];
                    }
                }
}

// ---------------------------------------------------------------------------
// Per-row: d'[c] = sum_s crossh[s][b][c] - 0.5*m2[c].  z^2 cancels exactly in
// loss_cls; its mean is applied in finalize.  outB = LSE(d') + sldj[b].
// ---------------------------------------------------------------------------
__global__ __launch_bounds__(256) void row_lse_kernel(
        const _Float16* __restrict__ crossh, const float* __restrict__ m2,
        const int* __restrict__ labels, const float* __restrict__ sldj,
        float* __restrict__ outA, float* __restrict__ outB) {
    const int row = blockIdx.x;
    const int tid = threadIdx.x;

    float a0 = 0.f, a1 = 0.f, a2 = 0.f, a3 = 0.f;
#pragma unroll
    for (int s = 0; s < NSL; ++s) {
        f16x4 h = ((const f16x4*)(crossh + ((size_t)s * NB + row) * NCP))[tid];
        a0 += (float)h.x; a1 += (float)h.y; a2 += (float)h.z; a3 += (float)h.w;
    }
    float4 mm = ((const float4*)m2)[tid];
    float4 v;
    v.x = a0 - 0.5f * mm.x;
    v.y = a1 - 0.5f * mm.y;
    v.z = a2 - 0.5f * mm.z;
    v.w = a3 - 0.5f * mm.w;

    float mx = fmaxf(fmaxf(v.x, v.y), fmaxf(v.z, v.w));
#pragma unroll
    for (int off = 32; off > 0; off >>= 1) mx = fmaxf(mx, __shfl_xor(mx, off, 64));
    __shared__ float smax[4], ssum[4];
    const int wid = tid >> 6, lane = tid & 63;
    if (lane == 0) smax[wid] = mx;
    __syncthreads();
    const float bm = fmaxf(fmaxf(smax[0], smax[1]), fmaxf(smax[2], smax[3]));

    float s = expf(v.x - bm) + expf(v.y - bm) + expf(v.z - bm) + expf(v.w - bm);
#pragma unroll
    for (int off = 32; off > 0; off >>= 1) s += __shfl_xor(s, off, 64);
    if (lane == 0) ssum[wid] = s;
    __syncthreads();
    if (tid == 0) {
        const float tot = ssum[0] + ssum[1] + ssum[2] + ssum[3];
        const float lpz = bm + logf(tot);
        const int lab = labels[row];
        float pick = 0.f;
#pragma unroll
        for (int si = 0; si < NSL; ++si)
            pick += (float)crossh[((size_t)si * NB + row) * NCP + lab];
        pick -= 0.5f * m2[lab];
        outA[row] = lpz - pick;
        outB[row] = lpz + sldj[row];
    }
}

// ---------------------------------------------------------------------------
// Deterministic final reduction. loss_cls = mean(outA);
// mean(log_pz + sldj) = mean(outB) - 0.5*mean(z2);  loss_gen = -that/ND.
// ---------------------------------------------------------------------------
__global__ __launch_bounds__(1024) void finalize_kernel(
        const float* __restrict__ a, const float* __restrict__ b,
        const float* __restrict__ z2, const float* __restrict__ beta,
        float* __restrict__ out) {
    __shared__ float sa[1024], sb[1024], sz[1024];
    const int tid = threadIdx.x;
    float va = 0.f, vb = 0.f, vz = 0.f;
    for (int i = tid; i < NB; i += 1024) {
        va += a[i]; vb += b[i]; vz += z2[i];
    }
    sa[tid] = va; sb[tid] = vb; sz[tid] = vz;
    __syncthreads();
    for (int s = 512; s > 0; s >>= 1) {
        if (tid < s) {
            sa[tid] += sa[tid + s];
            sb[tid] += sb[tid + s];
            sz[tid] += sz[tid + s];
        }
        __syncthreads();
    }
    if (tid == 0) {
        const float loss_cls = sa[0] / (float)NB;
        const float mean_lpz_sldj = sb[0] / (float)NB - 0.5f * (sz[0] / (float)NB);
        const float loss_gen = -mean_lpz_sldj / (float)ND;
        const float total = loss_gen + beta[0] * loss_cls;
        out[0] = total;
        out[1] = loss_gen;
        out[2] = loss_cls;
    }
}

extern "C" void kernel_launch(void* const* d_in, const int* in_sizes, int n_in,
                              void* d_out, int out_size, void* d_ws, size_t ws_size,
                              hipStream_t stream) {
    const float* z      = (const float*)d_in[0];
    const float* sldj   = (const float*)d_in[1];
    const int*   labels = (const int*)d_in[2];
    const float* beta   = (const float*)d_in[3];
    const float* means  = (const float*)d_in[4];
    float* out = (float*)d_out;

    char* ws = (char*)d_ws;
    size_t off = 0;
    u16* zb = (u16*)(ws + off);           off += (size_t)NB * ND * 2;          // 25.2 MB
    u16* mb = (u16*)(ws + off);           off += (size_t)NCP * ND * 2;         //  6.3 MB
    float* z2 = (float*)(ws + off);       off += (size_t)NB * 4;
    float* m2 = (float*)(ws + off);       off += (size_t)NCP * 4;
    _Float16* crossh = (_Float16*)(ws + off); off += (size_t)NSL * NB * NCP * 2; // 33.6 MB
    float* ra = (float*)(ws + off);       off += (size_t)NB * 4;
    float* rb = (float*)(ws + off);       off += (size_t)NB * 4;

    convert_all_kernel<<<NB + NCP, 256, 0, stream>>>(z, means, zb, mb, z2, m2);
    gemm_kernel<<<256, 512, 0, stream>>>(zb, mb, crossh);
    row_lse_kernel<<<NB, 256, 0, stream>>>(crossh, m2, labels, sldj, ra, rb);
    finalize_kernel<<<1, 1024, 0, stream>>>(ra, rb, z2, beta, out);
}

// Round 14
// 60.180 us; speedup vs baseline: 1.1058x; 1.1058x over previous
//
#include <hip/hip_runtime.h>
#include <hip/hip_bf16.h>
#include <cstdint>
#include <cstddef>

#define NB 4096     // batch rows
#define NC 1000     // real classes
#define NCP 1024    // padded classes
#define ND 3072     // feature dim
#define NSL 4       // split-K slices
#define KSL (ND / NSL)   // 768
#define BM 256
#define BN 256
#define BK 32
#define NT (KSL / BK)    // 24 K-steps per slice
#define ABUF (BM * BK)   // 8192 elems (16 KiB bf16)
#define BBUF (BN * BK)

typedef __attribute__((ext_vector_type(8))) __bf16 bf16x8;
typedef __attribute__((ext_vector_type(4))) float f32x4;
typedef __attribute__((ext_vector_type(4))) unsigned short u16x4;
typedef __attribute__((ext_vector_type(4))) _Float16 f16x4;
typedef unsigned short u16;

__device__ __forceinline__ u16 f2bf_rne(float x) {
    uint32_t u = __float_as_uint(x);
    uint32_t r = (u + 0x7fffu + ((u >> 16) & 1u)) >> 16;
    return (u16)r;
}

// ---------------------------------------------------------------------------
// Fused convert: blocks [0,NB) convert z rows (z2 = ||z||^2); blocks
// [NB, NB+NCP) convert means rows (rows >= NC zero-padded, m2 = 1e30 kills
// padded classes in the LSE).
// ---------------------------------------------------------------------------
__global__ __launch_bounds__(256) void convert_all_kernel(
        const float* __restrict__ z, const float* __restrict__ means,
        u16* __restrict__ zb, u16* __restrict__ mb,
        float* __restrict__ z2, float* __restrict__ m2) {
    const int bidx = blockIdx.x;
    const int tid = threadIdx.x;
    const float* src;
    u16* dst;
    float* sq;
    bool pad = false;
    if (bidx < NB) {
        src = z + (size_t)bidx * ND;
        dst = zb + (size_t)bidx * ND;
        sq = z2 + bidx;
    } else {
        const int mr = bidx - NB;
        dst = mb + (size_t)mr * ND;
        sq = m2 + mr;
        src = means + (size_t)mr * ND;
        pad = (mr >= NC);
    }
    if (!pad) {
        const float4* s = (const float4*)src;
        float acc = 0.f;
#pragma unroll
        for (int i = 0; i < 3; ++i) {                // 768 float4 / 256 threads
            const int idx = tid + i * 256;
            float4 v = s[idx];
            acc = fmaf(v.x, v.x, acc);
            acc = fmaf(v.y, v.y, acc);
            acc = fmaf(v.z, v.z, acc);
            acc = fmaf(v.w, v.w, acc);
            u16x4 o;
            o.x = f2bf_rne(v.x); o.y = f2bf_rne(v.y);
            o.z = f2bf_rne(v.z); o.w = f2bf_rne(v.w);
            *(u16x4*)(dst + idx * 4) = o;
        }
#pragma unroll
        for (int off = 32; off > 0; off >>= 1) acc += __shfl_xor(acc, off, 64);
        __shared__ float ssum[4];
        const int wid = tid >> 6, lane = tid & 63;
        if (lane == 0) ssum[wid] = acc;
        __syncthreads();
        if (tid == 0) sq[0] = ssum[0] + ssum[1] + ssum[2] + ssum[3];
    } else {
        u16x4 z4 = (u16x4){0, 0, 0, 0};
#pragma unroll
        for (int i = 0; i < 3; ++i) *(u16x4*)(dst + (tid + i * 256) * 4) = z4;
        if (tid == 0) sq[0] = 1e30f;
    }
}

// ---------------------------------------------------------------------------
// crossh[s][b][c] = (f16) sum over K-slice s of z_b . mu_c  (raw partials).
// BEST-MEASURED CONFIG (R10, 60.4 us total): 256x256 tile (staged bytes
// 201 MB vs 402 at 128x128), 16 waves (1024 thr, 4x4 grid of the verified
// 64x64 wave tile), BK=32, 4 LDS buffers (128 KiB), depth-3 counted-vmcnt
// pipeline (vmcnt 4/2/0), one raw s_barrier per K-step. NSL=4 -> grid 256.
// T2 XOR swizzle: phys slot p holds k-slot s = p ^ ((r>>1)&3) (0-conflict
// verified). Perturbations measured WORSE: 8 waves/128x64 (R11), depth-4
// +setprio (R12), 8-phase port (R13) — short K-slice (NT=24) keeps this
// depth-3 barrier-lockstep variant the local optimum.
// ---------------------------------------------------------------------------
#define GLOAD_LDS16(gp, lp)                                            \
    __builtin_amdgcn_global_load_lds(                                  \
        (const __attribute__((address_space(1))) void*)(gp),           \
        (__attribute__((address_space(3))) void*)(lp), 16, 0, 0)

__global__ __launch_bounds__(1024, 4) void gemm_kernel(
        const u16* __restrict__ zb, const u16* __restrict__ mb,
        _Float16* __restrict__ crossh) {
    __shared__ u16 As[4 * ABUF];   // 64 KiB (4 buffers)
    __shared__ u16 Bs[4 * BBUF];   // 64 KiB

    const int tid  = threadIdx.x;
    const int wid  = tid >> 6;
    const int lane = tid & 63;
    const int wrr  = (wid >> 2) * 64;    // wave row offset (0..192)
    const int wcc  = (wid & 3) * 64;     // wave col offset (0..192)
    const int lrow = lane & 15;          // fragment row index
    const int kgrp = lane >> 4;          // k-group 0..3

    // XCD-chunked work: 32 consecutive w per XCD (half a K-slice: 8 brows x
    // 4 bcols share panels within one XCD's L2).
    const int bid = blockIdx.x;
    const int w = (bid & 7) * 32 + (bid >> 3);
    const int ksl  = w >> 6;
    const int rem  = w & 63;
    const int brow = (rem >> 2) * BM;
    const int bcol = (rem & 3) * BN;
    const int kbase = ksl * KSL;

    f32x4 acc[4][4];
#pragma unroll
    for (int m = 0; m < 4; ++m)
#pragma unroll
        for (int n = 0; n < 4; ++n) acc[m][n] = (f32x4){0.f, 0.f, 0.f, 0.f};

    // Staging: chunk c = tid (16B) -> row r = c>>2, phys slot p = c&3.
    // Physical slot p holds global k-slot s = p ^ ((r>>1)&3) (XOR involution,
    // DMA-linear dest; verified 0 bank conflicts).
    const u16* gA;
    const u16* gB;
    u16* lA;
    u16* lB;
    {
        const int r = tid >> 2, p = tid & 3, s = p ^ ((r >> 1) & 3);
        gA = zb + (size_t)(brow + r) * ND + kbase + s * 8;
        gB = mb + (size_t)(bcol + r) * ND + kbase + s * 8;
        lA = As + wid * 512;     // wave-uniform base (buf 0): 64 chunks/wave
        lB = Bs + wid * 512;
    }

#define STAGE(tt) do {                                                   \
        const int bb_ = (tt) & 3;                                        \
        const int ko_ = (tt) * BK;                                       \
        GLOAD_LDS16(gA + ko_, lA + bb_ * ABUF);                          \
        GLOAD_LDS16(gB + ko_, lB + bb_ * BBUF);                          \
    } while (0)

#define COMP(tt) do {                                                    \
        const int cb_ = (tt) & 3;                                        \
        const u16* Ac = As + cb_ * ABUF;                                 \
        const u16* Bc = Bs + cb_ * BBUF;                                 \
        const int pk = kgrp ^ ((lrow >> 1) & 3);                         \
        bf16x8 a0 = *(const bf16x8*)&Ac[(wrr +  0 + lrow) * BK + pk * 8]; \
        bf16x8 a1 = *(const bf16x8*)&Ac[(wrr + 16 + lrow) * BK + pk * 8]; \
        bf16x8 a2 = *(const bf16x8*)&Ac[(wrr + 32 + lrow) * BK + pk * 8]; \
        bf16x8 a3 = *(const bf16x8*)&Ac[(wrr + 48 + lrow) * BK + pk * 8]; \
        _Pragma("unroll")                                                \
        for (int n = 0; n < 4; ++n) {                                    \
            bf16x8 bn = *(const bf16x8*)&Bc[(wcc + n * 16 + lrow) * BK + pk * 8]; \
            acc[0][n] = __builtin_amdgcn_mfma_f32_16x16x32_bf16(a0, bn, acc[0][n], 0, 0, 0); \
            acc[1][n] = __builtin_amdgcn_mfma_f32_16x16x32_bf16(a1, bn, acc[1][n], 0, 0, 0); \
            acc[2][n] = __builtin_amdgcn_mfma_f32_16x16x32_bf16(a2, bn, acc[2][n], 0, 0, 0); \
            acc[3][n] = __builtin_amdgcn_mfma_f32_16x16x32_bf16(a3, bn, acc[3][n], 0, 0, 0); \
        }                                                                \
    } while (0)

    // prologue: stage tiles 0,1,2 into buffers 0,1,2 (6 loads/thread in flight)
    STAGE(0); STAGE(1); STAGE(2);

    // main loop: counted vmcnt — tiles t+1, t+2 stay in flight across barrier
    for (int t = 0; t < NT - 2; ++t) {
        asm volatile("s_waitcnt vmcnt(4)" ::: "memory");   // tile t landed
        __builtin_amdgcn_s_barrier();      // tile t visible; buf (t+3)&3 free
        __builtin_amdgcn_sched_barrier(0);
        if (t + 3 < NT) STAGE(t + 3);
        __builtin_amdgcn_sched_barrier(0);
        COMP(t);
    }
    // tail: t = NT-2, NT-1
    asm volatile("s_waitcnt vmcnt(2)" ::: "memory");
    __builtin_amdgcn_s_barrier();
    __builtin_amdgcn_sched_barrier(0);
    COMP(NT - 2);
    asm volatile("s_waitcnt vmcnt(0)" ::: "memory");
    __builtin_amdgcn_s_barrier();
    __builtin_amdgcn_sched_barrier(0);
    COMP(NT - 1);

#undef STAGE
#undef COMP

    // epilogue: C/D layout col = lane&15, row = (lane>>4)*4 + r  (f16 partial)
    _Float16* outp = crossh + (size_t)ksl * NB * NCP;
#pragma unroll
    for (int n = 0; n < 4; ++n) {
        const int gcol = bcol + wcc + n * 16 + lrow;
#pragma unroll
        for (int m = 0; m < 4; ++m) {
#pragma unroll
            for (int r = 0; r < 4; ++r) {
                const int grow = brow + wrr + m * 16 + kgrp * 4 + r;
                outp[(size_t)grow * NCP + gcol] = (_Float16)acc[m][n][r];
            }
        }
    }
}

// ---------------------------------------------------------------------------
// Per-row: d'[c] = sum_s crossh[s][b][c] - 0.5*m2[c].  z^2 cancels exactly in
// loss_cls (outA = LSE(d') - d'[label]); its mean is applied in finalize for
// loss_gen.  outB = LSE(d') + sldj[b].
// ---------------------------------------------------------------------------
__global__ __launch_bounds__(256) void row_lse_kernel(
        const _Float16* __restrict__ crossh, const float* __restrict__ m2,
        const int* __restrict__ labels, const float* __restrict__ sldj,
        float* __restrict__ outA, float* __restrict__ outB) {
    const int row = blockIdx.x;
    const int tid = threadIdx.x;

    float a0 = 0.f, a1 = 0.f, a2 = 0.f, a3 = 0.f;
#pragma unroll
    for (int s = 0; s < NSL; ++s) {
        f16x4 h = ((const f16x4*)(crossh + ((size_t)s * NB + row) * NCP))[tid];
        a0 += (float)h.x; a1 += (float)h.y; a2 += (float)h.z; a3 += (float)h.w;
    }
    float4 mm = ((const float4*)m2)[tid];
    float4 v;
    v.x = a0 - 0.5f * mm.x;
    v.y = a1 - 0.5f * mm.y;
    v.z = a2 - 0.5f * mm.z;
    v.w = a3 - 0.5f * mm.w;

    float mx = fmaxf(fmaxf(v.x, v.y), fmaxf(v.z, v.w));
#pragma unroll
    for (int off = 32; off > 0; off >>= 1) mx = fmaxf(mx, __shfl_xor(mx, off, 64));
    __shared__ float smax[4], ssum[4];
    const int wid = tid >> 6, lane = tid & 63;
    if (lane == 0) smax[wid] = mx;
    __syncthreads();
    const float bm = fmaxf(fmaxf(smax[0], smax[1]), fmaxf(smax[2], smax[3]));

    float s = expf(v.x - bm) + expf(v.y - bm) + expf(v.z - bm) + expf(v.w - bm);
#pragma unroll
    for (int off = 32; off > 0; off >>= 1) s += __shfl_xor(s, off, 64);
    if (lane == 0) ssum[wid] = s;
    __syncthreads();
    if (tid == 0) {
        const float tot = ssum[0] + ssum[1] + ssum[2] + ssum[3];
        const float lpz = bm + logf(tot);
        const int lab = labels[row];
        float pick = 0.f;
#pragma unroll
        for (int si = 0; si < NSL; ++si)
            pick += (float)crossh[((size_t)si * NB + row) * NCP + lab];
        pick -= 0.5f * m2[lab];
        outA[row] = lpz - pick;
        outB[row] = lpz + sldj[row];
    }
}

// ---------------------------------------------------------------------------
// Deterministic final reduction. loss_cls = mean(outA);
// mean(log_pz + sldj) = mean(outB) - 0.5*mean(z2);  loss_gen = -that/ND.
// ---------------------------------------------------------------------------
__global__ __launch_bounds__(1024) void finalize_kernel(
        const float* __restrict__ a, const float* __restrict__ b,
        const float* __restrict__ z2, const float* __restrict__ beta,
        float* __restrict__ out) {
    __shared__ float sa[1024], sb[1024], sz[1024];
    const int tid = threadIdx.x;
    float va = 0.f, vb = 0.f, vz = 0.f;
    for (int i = tid; i < NB; i += 1024) {
        va += a[i]; vb += b[i]; vz += z2[i];
    }
    sa[tid] = va; sb[tid] = vb; sz[tid] = vz;
    __syncthreads();
    for (int s = 512; s > 0; s >>= 1) {
        if (tid < s) {
            sa[tid] += sa[tid + s];
            sb[tid] += sb[tid + s];
            sz[tid] += sz[tid + s];
        }
        __syncthreads();
    }
    if (tid == 0) {
        const float loss_cls = sa[0] / (float)NB;
        const float mean_lpz_sldj = sb[0] / (float)NB - 0.5f * (sz[0] / (float)NB);
        const float loss_gen = -mean_lpz_sldj / (float)ND;
        const float total = loss_gen + beta[0] * loss_cls;
        out[0] = total;
        out[1] = loss_gen;
        out[2] = loss_cls;
    }
}

extern "C" void kernel_launch(void* const* d_in, const int* in_sizes, int n_in,
                              void* d_out, int out_size, void* d_ws, size_t ws_size,
                              hipStream_t stream) {
    const float* z      = (const float*)d_in[0];
    const float* sldj   = (const float*)d_in[1];
    const int*   labels = (const int*)d_in[2];
    const float* beta   = (const float*)d_in[3];
    const float* means  = (const float*)d_in[4];
    float* out = (float*)d_out;

    char* ws = (char*)d_ws;
    size_t off = 0;
    u16* zb = (u16*)(ws + off);           off += (size_t)NB * ND * 2;          // 25.2 MB
    u16* mb = (u16*)(ws + off);           off += (size_t)NCP * ND * 2;         //  6.3 MB
    float* z2 = (float*)(ws + off);       off += (size_t)NB * 4;
    float* m2 = (float*)(ws + off);       off += (size_t)NCP * 4;
    _Float16* crossh = (_Float16*)(ws + off); off += (size_t)NSL * NB * NCP * 2; // 33.6 MB
    float* ra = (float*)(ws + off);       off += (size_t)NB * 4;
    float* rb = (float*)(ws + off);       off += (size_t)NB * 4;

    convert_all_kernel<<<NB + NCP, 256, 0, stream>>>(z, means, zb, mb, z2, m2);
    gemm_kernel<<<8 * 32 * NSL / 4, 1024, 0, stream>>>(zb, mb, crossh);
    row_lse_kernel<<<NB, 256, 0, stream>>>(crossh, m2, labels, sldj, ra, rb);
    finalize_kernel<<<1, 1024, 0, stream>>>(ra, rb, z2, beta, out);
}